// Round 4
// baseline (458.739 us; speedup 1.0000x reference)
//
#include <hip/hip_runtime.h>
#include <math.h>

#define NLEV 24
#define CAPM 262144
#define HID 32

// ws layout: float ws[0..23] = 1/scale, ws[24..47] = c2f window, ws[48] = La;
// float2 feat[NLEV][N] starting at ws + 256 floats.
__global__ void init_consts(const int* __restrict__ iter_p, float* __restrict__ ws) {
    __shared__ float wloc[NLEV];
    int l = threadIdx.x;
    if (l < NLEV) {
        double scale;
        if (l == 0) scale = 1.0;
        else if (l == NLEV - 1) scale = 0.0001;
        else scale = pow(10.0, -((double)(4 * l)) / 23.0);
        float scale_f = (float)scale;                 // reference casts geomspace to fp32
        ws[l] = (float)(1.0 / (double)scale_f);       // correctly-rounded fp32 reciprocal
        float t = (float)iter_p[0] / 10000.0f;
        t = fminf(fmaxf(t, 0.0f), 1.0f);
        float alpha = (0.3f + 0.7f * t) * 24.0f;
        float x = fminf(fmaxf(alpha - (float)l, 0.0f), 1.0f);
        float win = 0.5f * (1.0f - (float)cos(M_PI * (double)x));
        ws[NLEV + l] = win;
        wloc[l] = win;
    }
    __syncthreads();
    if (l == 0) {
        int cnt = 0;
        for (int i = 0; i < NLEV; i++) cnt += (wloc[i] > 0.0f) ? 1 : 0;
        ws[2 * NLEV] = (float)cnt;
    }
}

__device__ __forceinline__ float gelu_exact(float v) {
    return 0.5f * v * (1.0f + erff(v * 0.70710678118654752f));
}

// Permutohedral lattice setup: 4 hash indices + barycentric weights
// (pre-multiplied by the c2f window). Verified arithmetic from round 1/3.
__device__ __forceinline__ void level_setup(
    float px, float py, float pz,
    const float* __restrict__ shifts, const float* __restrict__ cons, int l,
    float* __restrict__ wgt /*4*/, unsigned* __restrict__ hh /*4*/)
{
    const float SF0 = 2.3094010767585034f;  // 4/sqrt(3)
    const float SF1 = 1.3333333333333333f;  // 4/3
    const float SF2 = 0.9428090415820634f;  // 2*sqrt(2)/3

    float win = cons[NLEV + l];
    float inv = cons[l];
    float p0 = fmaf(px, inv, shifts[3 * l + 0]);
    float p1 = fmaf(py, inv, shifts[3 * l + 1]);
    float p2 = fmaf(pz, inv, shifts[3 * l + 2]);
    float c0 = p0 * SF0, c1 = p1 * SF1, c2 = p2 * SF2;
    float s1 = c1 + c2;
    float s0 = c0 + s1;
    float e0 = s0;
    float e1 = s1 - c0;
    float e2 = c2 - 2.0f * c1;
    float e3 = -3.0f * c2;
    float r0f = rintf(e0 * 0.25f) * 4.0f;
    float r1f = rintf(e1 * 0.25f) * 4.0f;
    float r2f = rintf(e2 * 0.25f) * 4.0f;
    float r3f = rintf(e3 * 0.25f) * 4.0f;
    int sum_ = (int)rintf((r0f + r1f + r2f + r3f) * 0.25f);
    float d0 = e0 - r0f, d1 = e1 - r1f, d2 = e2 - r2f, d3 = e3 - r3f;
    int k0 = (int)(d1 > d0) + (int)(d2 > d0) + (int)(d3 > d0) + sum_;
    int k1 = (int)(d0 > d1) + (int)(d2 > d1) + (int)(d3 > d1)
           + (int)(d0 == d1) + sum_;
    int k2 = (int)(d0 > d2) + (int)(d1 > d2) + (int)(d3 > d2)
           + (int)(d0 == d2) + (int)(d1 == d2) + sum_;
    int k3 = (int)(d0 > d3) + (int)(d1 > d3) + (int)(d2 > d3)
           + (int)(d0 == d3) + (int)(d1 == d3) + (int)(d2 == d3) + sum_;
    int a0 = (k0 < 0) ? 4 : ((k0 > 3) ? -4 : 0); k0 += a0; r0f += (float)a0;
    int a1 = (k1 < 0) ? 4 : ((k1 > 3) ? -4 : 0); k1 += a1; r1f += (float)a1;
    int a2 = (k2 < 0) ? 4 : ((k2 > 3) ? -4 : 0); k2 += a2; r2f += (float)a2;
    int a3 = (k3 < 0) ? 4 : ((k3 > 3) ? -4 : 0); k3 += a3; r3f += (float)a3;

    float dl0 = (e0 - r0f) * 0.25f;
    float dl1 = (e1 - r1f) * 0.25f;
    float dl2 = (e2 - r2f) * 0.25f;
    float dl3 = (e3 - r3f) * 0.25f;

    float q0 = (k0 == 3) ? dl0 : ((k1 == 3) ? dl1 : ((k2 == 3) ? dl2 : dl3));
    float q1 = (k0 == 2) ? dl0 : ((k1 == 2) ? dl1 : ((k2 == 2) ? dl2 : dl3));
    float q2 = (k0 == 1) ? dl0 : ((k1 == 1) ? dl1 : ((k2 == 1) ? dl2 : dl3));
    float q3 = (k0 == 0) ? dl0 : ((k1 == 0) ? dl1 : ((k2 == 0) ? dl2 : dl3));
    wgt[0] = (q0 + (1.0f - q3)) * win;
    wgt[1] = (q1 - q0) * win;
    wgt[2] = (q2 - q1) * win;
    wgt[3] = (q3 - q2) * win;

    int i0 = (int)r0f, i1 = (int)r1f, i2 = (int)r2f;
    const unsigned P1 = 2654435761u, P2 = 805459861u;
    hh[0] = ((unsigned)i0 ^ ((unsigned)i1 * P1) ^ ((unsigned)i2 * P2)) & (CAPM - 1);
    int b0 = i0 + 1 - ((k0 > 2) ? 4 : 0);
    int b1v = i1 + 1 - ((k1 > 2) ? 4 : 0);
    int b2v = i2 + 1 - ((k2 > 2) ? 4 : 0);
    hh[1] = ((unsigned)b0 ^ ((unsigned)b1v * P1) ^ ((unsigned)b2v * P2)) & (CAPM - 1);
    int c0i = i0 + 2 - ((k0 > 1) ? 4 : 0);
    int c1i = i1 + 2 - ((k1 > 1) ? 4 : 0);
    int c2i = i2 + 2 - ((k2 > 1) ? 4 : 0);
    hh[2] = ((unsigned)c0i ^ ((unsigned)c1i * P1) ^ ((unsigned)c2i * P2)) & (CAPM - 1);
    int e0i = i0 + 3 - ((k0 > 0) ? 4 : 0);
    int e1i = i1 + 3 - ((k1 > 0) ? 4 : 0);
    int e2i = i2 + 3 - ((k2 > 0) ? 4 : 0);
    hh[3] = ((unsigned)e0i ^ ((unsigned)e1i * P1) ^ ((unsigned)e2i * P2)) & (CAPM - 1);
}

// Phase 1: level-major encode. Grid = 3 segments x (8 * nb) blocks.
// level = seg*8 + (within % 8)  ->  under round-robin block->XCD dispatch,
// each XCD works one level at a time; its 2 MB table fits the 4 MB L2.
__global__ __launch_bounds__(256)
void encode_levels(const float* __restrict__ points,
                   const float* __restrict__ tables,
                   const float* __restrict__ shifts,
                   const float* __restrict__ cons,
                   float2* __restrict__ feat, int N, int nb)
{
    int gb = blockIdx.x;
    int seg = gb / (8 * nb);
    int within = gb - seg * 8 * nb;
    int level = seg * 8 + (within & 7);
    int pb = within >> 3;
    float win = cons[NLEV + level];
    if (win == 0.0f) return;                 // inactive level: nothing read downstream
    int pid = pb * 256 + threadIdx.x;
    if (pid >= N) return;

    float px = points[3 * pid + 0];
    float py = points[3 * pid + 1];
    float pz = points[3 * pid + 2];

    float wgt[4]; unsigned hh[4];
    level_setup(px, py, pz, shifts, cons, level, wgt, hh);
    const float2* tab = (const float2*)tables + (size_t)level * CAPM;
    float2 g0 = tab[hh[0]];
    float2 g1 = tab[hh[1]];
    float2 g2 = tab[hh[2]];
    float2 g3 = tab[hh[3]];
    float f0 = wgt[0] * g0.x + wgt[1] * g1.x + wgt[2] * g2.x + wgt[3] * g3.x;
    float f1 = wgt[0] * g0.y + wgt[1] * g1.y + wgt[2] * g2.y + wgt[3] * g3.y;
    feat[(size_t)level * N + pid] = make_float2(f0, f1);
}

// Phase 2: MLP. Coalesced feature reads, per-thread scalar FMAs.
__global__ __launch_bounds__(256)
void mlp_kernel(const float* __restrict__ points,
                const float2* __restrict__ feat,
                const float* __restrict__ w1, const float* __restrict__ b1,
                const float* __restrict__ w2, const float* __restrict__ b2,
                const float* __restrict__ w3, const float* __restrict__ b3,
                const float* __restrict__ w4, const float* __restrict__ b4,
                const float* __restrict__ cons,
                float* __restrict__ out, int N)
{
    int pid = blockIdx.x * blockDim.x + threadIdx.x;
    if (pid >= N) return;

    float px = points[3 * pid + 0];
    float py = points[3 * pid + 1];
    float pz = points[3 * pid + 2];

    float h1[HID];
    float cx = px * 0.001f, cy = py * 0.001f, cz = pz * 0.001f;
    #pragma unroll
    for (int j = 0; j < HID; j++) {
        float v = b1[j];
        v = fmaf(cx, w1[48 * HID + j], v);
        v = fmaf(cy, w1[49 * HID + j], v);
        v = fmaf(cz, w1[50 * HID + j], v);
        h1[j] = v;
    }

    int La = (int)cons[2 * NLEV];
    for (int l = 0; l < La; ++l) {
        float2 f = feat[(size_t)l * N + pid];    // coalesced
        const float* wr0 = w1 + (size_t)(2 * l) * HID;
        const float* wr1 = wr0 + HID;
        #pragma unroll
        for (int j = 0; j < HID; j++)
            h1[j] = fmaf(f.y, wr1[j], fmaf(f.x, wr0[j], h1[j]));
    }

    float g[HID];
    #pragma unroll
    for (int i = 0; i < HID; i++) g[i] = gelu_exact(h1[i]);
    float h2[HID];
    #pragma unroll
    for (int j = 0; j < HID; j++) h2[j] = b2[j];
    #pragma unroll
    for (int i = 0; i < HID; i++) {
        float gi = g[i];
        #pragma unroll
        for (int j = 0; j < HID; j++) h2[j] = fmaf(gi, w2[i * HID + j], h2[j]);
    }
    #pragma unroll
    for (int i = 0; i < HID; i++) g[i] = gelu_exact(h2[i]);
    #pragma unroll
    for (int j = 0; j < HID; j++) h1[j] = b3[j];
    #pragma unroll
    for (int i = 0; i < HID; i++) {
        float gi = g[i];
        #pragma unroll
        for (int j = 0; j < HID; j++) h1[j] = fmaf(gi, w3[i * HID + j], h1[j]);
    }
    #pragma unroll
    for (int i = 0; i < HID; i++) g[i] = gelu_exact(h1[i]);
    float o[33];
    #pragma unroll
    for (int j = 0; j < 33; j++) o[j] = b4[j];
    #pragma unroll
    for (int i = 0; i < HID; i++) {
        float gi = g[i];
        #pragma unroll
        for (int j = 0; j < 33; j++) o[j] = fmaf(gi, w4[i * 33 + j], o[j]);
    }

    out[pid] = o[0];
    float* geo = out + N + (size_t)pid * 32;
    #pragma unroll
    for (int j = 0; j < 32; j += 4) {
        float4 v = make_float4(o[1 + j], o[2 + j], o[3 + j], o[4 + j]);
        *reinterpret_cast<float4*>(geo + j) = v;
    }
}

// Fallback: round-3 verified fused kernel (used only if ws too small).
__global__ __launch_bounds__(256)
void sdf_fused(const float* __restrict__ points,
               const float* __restrict__ tables,
               const float* __restrict__ shifts,
               const float* __restrict__ w1, const float* __restrict__ b1,
               const float* __restrict__ w2, const float* __restrict__ b2,
               const float* __restrict__ w3, const float* __restrict__ b3,
               const float* __restrict__ w4, const float* __restrict__ b4,
               const float* __restrict__ cons,
               float* __restrict__ out, int N)
{
    int pid = blockIdx.x * blockDim.x + threadIdx.x;
    if (pid >= N) return;
    float px = points[3 * pid + 0];
    float py = points[3 * pid + 1];
    float pz = points[3 * pid + 2];
    float h1[HID];
    float cx = px * 0.001f, cy = py * 0.001f, cz = pz * 0.001f;
    #pragma unroll
    for (int j = 0; j < HID; j++) {
        float v = b1[j];
        v = fmaf(cx, w1[48 * HID + j], v);
        v = fmaf(cy, w1[49 * HID + j], v);
        v = fmaf(cz, w1[50 * HID + j], v);
        h1[j] = v;
    }
    int La = (int)cons[2 * NLEV];
    #pragma unroll 2
    for (int l = 0; l < La; ++l) {
        float wgt[4]; unsigned hh[4];
        level_setup(px, py, pz, shifts, cons, l, wgt, hh);
        const float2* tab = (const float2*)tables + (size_t)l * CAPM;
        float2 g0 = tab[hh[0]], g1 = tab[hh[1]], g2 = tab[hh[2]], g3 = tab[hh[3]];
        float f0 = wgt[0] * g0.x + wgt[1] * g1.x + wgt[2] * g2.x + wgt[3] * g3.x;
        float f1 = wgt[0] * g0.y + wgt[1] * g1.y + wgt[2] * g2.y + wgt[3] * g3.y;
        const float* wr0 = w1 + (size_t)(2 * l) * HID;
        const float* wr1 = wr0 + HID;
        #pragma unroll
        for (int j = 0; j < HID; j++)
            h1[j] = fmaf(f1, wr1[j], fmaf(f0, wr0[j], h1[j]));
    }
    float g[HID];
    #pragma unroll
    for (int i = 0; i < HID; i++) g[i] = gelu_exact(h1[i]);
    float h2[HID];
    #pragma unroll
    for (int j = 0; j < HID; j++) h2[j] = b2[j];
    #pragma unroll
    for (int i = 0; i < HID; i++) {
        float gi = g[i];
        #pragma unroll
        for (int j = 0; j < HID; j++) h2[j] = fmaf(gi, w2[i * HID + j], h2[j]);
    }
    #pragma unroll
    for (int i = 0; i < HID; i++) g[i] = gelu_exact(h2[i]);
    #pragma unroll
    for (int j = 0; j < HID; j++) h1[j] = b3[j];
    #pragma unroll
    for (int i = 0; i < HID; i++) {
        float gi = g[i];
        #pragma unroll
        for (int j = 0; j < HID; j++) h1[j] = fmaf(gi, w3[i * HID + j], h1[j]);
    }
    #pragma unroll
    for (int i = 0; i < HID; i++) g[i] = gelu_exact(h1[i]);
    float o[33];
    #pragma unroll
    for (int j = 0; j < 33; j++) o[j] = b4[j];
    #pragma unroll
    for (int i = 0; i < HID; i++) {
        float gi = g[i];
        #pragma unroll
        for (int j = 0; j < 33; j++) o[j] = fmaf(gi, w4[i * 33 + j], o[j]);
    }
    out[pid] = o[0];
    float* geo = out + N + (size_t)pid * 32;
    #pragma unroll
    for (int j = 0; j < 32; j += 4) {
        float4 v = make_float4(o[1 + j], o[2 + j], o[3 + j], o[4 + j]);
        *reinterpret_cast<float4*>(geo + j) = v;
    }
}

extern "C" void kernel_launch(void* const* d_in, const int* in_sizes, int n_in,
                              void* d_out, int out_size, void* d_ws, size_t ws_size,
                              hipStream_t stream) {
    const float* points = (const float*)d_in[0];
    const int*   iter_p = (const int*)d_in[1];
    const float* tables = (const float*)d_in[2];
    const float* shifts = (const float*)d_in[3];
    const float* w1 = (const float*)d_in[4];
    const float* b1 = (const float*)d_in[5];
    const float* w2 = (const float*)d_in[6];
    const float* b2 = (const float*)d_in[7];
    const float* w3 = (const float*)d_in[8];
    const float* b3 = (const float*)d_in[9];
    const float* w4 = (const float*)d_in[10];
    const float* b4 = (const float*)d_in[11];
    float* out = (float*)d_out;
    float* ws  = (float*)d_ws;
    int N = in_sizes[0] / 3;

    init_consts<<<1, 64, 0, stream>>>(iter_p, ws);

    size_t needed = 1024 + (size_t)NLEV * (size_t)N * sizeof(float2);
    int nb = (N + 255) / 256;
    if (ws_size >= needed) {
        float2* feat = (float2*)(ws + 256);
        encode_levels<<<3 * 8 * nb, 256, 0, stream>>>(points, tables, shifts,
                                                      ws, feat, N, nb);
        mlp_kernel<<<nb, 256, 0, stream>>>(points, feat,
                                           w1, b1, w2, b2, w3, b3, w4, b4,
                                           ws, out, N);
    } else {
        sdf_fused<<<nb, 256, 0, stream>>>(points, tables, shifts,
                                          w1, b1, w2, b2, w3, b3, w4, b4,
                                          ws, out, N);
    }
}